// Round 19
// baseline (2450.207 us; speedup 1.0000x reference)
//
#include <hip/hip_runtime.h>
#include <hip/hip_bf16.h>

#define TT 128
#define DD 1024   // padded per-operand K
#define HH 1000
#define NBLK 252  // 2 layers x 2 batch-halves x 63 cell-groups (16 cells each)
#define RING 16   // h ring depth (window); inv every RING phases

typedef float f32x4 __attribute__((ext_vector_type(4)));
typedef __bf16 bf16x8 __attribute__((ext_vector_type(8)));

__device__ __forceinline__ bf16x8 asbf(f32x4 v) { return __builtin_bit_cast(bf16x8, v); }

// A-feed load: sc0 = L1-bypass, L2-CACHEABLE (L2 broadcasts; staleness cleared
// by one buffer_inv per XCD per RING phases — verified r14-r16).
__device__ __forceinline__ void ld_a(bf16x8* d, const char* p) {
    asm volatile("global_load_dwordx4 %0, %1, off sc0" : "=v"(*d) : "v"(p));
}
// h dword store as ATOMIC SWAP: executes at the L3 atomic unit -> h lands in
// L3 (not streamed to HBM). Coherence story unchanged (L2 copies still stale
// until window-boundary inv). vmcnt counts it like a store.
__device__ __forceinline__ void st_h32(char* p, unsigned v) {
    asm volatile("global_atomic_swap %0, %1, off" :: "v"(p), "v"(v) : "memory");
}
// barrier slot arrival: atomic swap (L3-resident slot)
__device__ __forceinline__ void st_ctl(unsigned* p, unsigned v) {
    asm volatile("global_atomic_swap %0, %1, off" :: "v"(p), "v"(v) : "memory");
}
// barrier slot poll: atomic umax(0) with return -> L3-executed fresh read
__device__ __forceinline__ unsigned ld_ctl(const unsigned* p) {
    unsigned old;
    asm volatile("global_atomic_umax %0, %1, %2, off sc0"
                 : "=v"(old) : "v"(p), "v"(0u) : "memory");
    return old;
}

#define AT_RLX __ATOMIC_RELAXED
#define SC_AGT __HIP_MEMORY_SCOPE_AGENT

// ---------------------------------------------------------------------------
__global__ void zero_ws(unsigned int* __restrict__ p, int nwords) {
    int i = blockIdx.x * blockDim.x + threadIdx.x;
    if (i < nwords) p[i] = 0u;
}

// ---------------------------------------------------------------------------
// cast x to bf16 in MFMA A-fragment order (verified):
// unit gid = ((t*32 + ks)*4 + mt)*64 + lane ; elem j = x[mt*16+(lane&15)][t][ks*32+(lane>>4)*8+j]
__global__ void cast_x(const float* __restrict__ x, __bf16* __restrict__ xfh) {
    int gid = blockIdx.x * 256 + threadIdx.x;     // 1,048,576 units
    int lane = gid & 63;
    int mt = (gid >> 6) & 3;
    int ks = (gid >> 8) & 31;
    int t  = gid >> 13;
    int row = mt * 16 + (lane & 15);
    int k0  = ks * 32 + (lane >> 4) * 8;
    const float* sp = x + ((size_t)row * TT + t) * 1024 + k0;
    float4 v0 = *(const float4*)sp;
    float4 v1 = *(const float4*)(sp + 4);
    float f[8] = {v0.x, v0.y, v0.z, v0.w, v1.x, v1.y, v1.z, v1.w};
    bf16x8 hv;
#pragma unroll
    for (int j = 0; j < 8; ++j) hv[j] = (__bf16)f[j];
    ((bf16x8*)xfh)[gid] = hv;
}

// ---------------------------------------------------------------------------
// Pack W/U into MFMA-B-fragment order via LDS tile (verified layout), bf16 hi:
// unit = (nt*256 + kb)*16 + col; col' = 4*cell + gate; kb<128 = W, kb>=128 = U.
__global__ __launch_bounds__(256) void pack_w2(
    const float* __restrict__ W1, const float* __restrict__ U1,
    const float* __restrict__ W2, const float* __restrict__ U2,
    __bf16* __restrict__ w1h, __bf16* __restrict__ w2h)
{
    int nt = blockIdx.x;          // 0..249
    int layer = blockIdx.y;       // 0..1
    const float* R1 = layer ? W2 : W1;
    const float* R2 = layer ? U2 : U1;
    int k1v = layer ? HH : 1024;
    __bf16* dh = layer ? w2h : w1h;
    int tid = threadIdx.x;

    __shared__ float lt[64][21];

    int kk = tid >> 2, g = tid & 3;           // load role: 64 k rows x 4 gates
    for (int c = 0; c < 32; ++c) {            // 64 k per iter
        int k = c * 64 + kk;
        float4 v = {0.f, 0.f, 0.f, 0.f};
        if (k < 1024) {
            if (k < k1v) v = *(const float4*)(R1 + (size_t)k * 4000 + g * 1000 + nt * 4);
        } else {
            int k2 = k - 1024;
            if (k2 < HH) v = *(const float4*)(R2 + (size_t)k2 * 4000 + g * 1000 + nt * 4);
        }
        lt[kk][g * 4 + 0] = v.x; lt[kk][g * 4 + 1] = v.y;
        lt[kk][g * 4 + 2] = v.z; lt[kk][g * 4 + 3] = v.w;
        __syncthreads();
        if (tid < 128) {
            int kbl = tid >> 4, col = tid & 15;
            int li = (col & 3) * 4 + (col >> 2);   // gate*4 + cell_local
            bf16x8 hv;
#pragma unroll
            for (int j = 0; j < 8; ++j) hv[j] = (__bf16)lt[kbl * 8 + j][li];
            size_t unit = ((size_t)nt * 256 + c * 8 + kbl) * 16 + col;
            ((bf16x8*)dh)[unit] = hv;
        }
        __syncthreads();
    }
}

// ---------------------------------------------------------------------------
// Persistent LSTM, batch-split (verified r16/r18): block = 32 batch rows x 16
// cells; W bf16 in AGPRs; one-stage 4-slab z reduction + direct h stores.
// NEW: all cross-XCD exchange (h stores, barrier slots) via L3 atomic units
// so the data is L3-resident — no HBM round trips on the critical path.
__global__ __launch_bounds__(256, 1) void lstm_persist(
    const __bf16* __restrict__ xfh,
    const __bf16* __restrict__ w1h, const __bf16* __restrict__ w2h,
    const float* __restrict__ b1, const float* __restrict__ b2,
    __bf16* hbuf, unsigned int* ctrl)
{
    unsigned* xcdm    = ctrl + 32;            // 8 registration counters
    unsigned* xcdFlag = ctrl + 384;           // 8 x 64B-strided flags
    unsigned* arr     = ctrl + 512;           // 256 x 16B-strided arrival slots

    const int bid = blockIdx.x;
    const int layer = bid >= 126;
    const int r0 = layer ? bid - 126 : bid;   // 0..125
    const int bh = r0 >= 63;                  // batch half
    const int nb = bh ? r0 - 63 : r0;         // 0..62 cell-group (16 cells)
    const int tid = threadIdx.x;
    const int lane = tid & 63, w = tid >> 6;
    const int op = w >> 1, kh = w & 1;
    const int ln = lane & 15, kg = lane >> 4;

    const char* h1ring = (const char*)hbuf;
    const char* h2ring = (const char*)(hbuf + (size_t)RING * 65536);

    // ---- startup: XCD registration (leader = first arriver on its XCD) ----
    __shared__ unsigned s_ldr;    // (xcd << 8) | is_leader
    if (tid == 0) {
        unsigned x;
        asm volatile("s_getreg_b32 %0, hwreg(HW_REG_XCC_ID)" : "=s"(x));
        x &= 7u;
        unsigned old = __hip_atomic_fetch_add(&xcdm[x], 1u, AT_RLX, SC_AGT);
        s_ldr = (x << 8) | (old == 0u ? 1u : 0u);
    }

    // ---- preload 4 weight tiles (bf16) into AGPRs: 4 x 16 ks x 4 regs = 256 ----
    const f32x4* wfh = (const f32x4*)(layer ? w2h : w1h);
    f32x4 WH[64];
#pragma unroll
    for (int tl = 0; tl < 4; ++tl) {
        int nt = nb * 4 + tl; if (nt > 249) nt = 249;
#pragma unroll
        for (int ks = 0; ks < 16; ++ks) {
            int kb = op * 128 + kh * 64 + ks * 4 + kg;
            WH[tl * 16 + ks] = wfh[((size_t)nt * 256 + kb) * 16 + ln];
        }
    }
#define PIN8(p0,p1,p2,p3,p4,p5,p6,p7) \
    asm volatile("" : "+a"(p0),"+a"(p1),"+a"(p2),"+a"(p3),"+a"(p4),"+a"(p5),"+a"(p6),"+a"(p7))
    PIN8(WH[0],WH[1],WH[2],WH[3],WH[4],WH[5],WH[6],WH[7]);
    PIN8(WH[8],WH[9],WH[10],WH[11],WH[12],WH[13],WH[14],WH[15]);
    PIN8(WH[16],WH[17],WH[18],WH[19],WH[20],WH[21],WH[22],WH[23]);
    PIN8(WH[24],WH[25],WH[26],WH[27],WH[28],WH[29],WH[30],WH[31]);
    PIN8(WH[32],WH[33],WH[34],WH[35],WH[36],WH[37],WH[38],WH[39]);
    PIN8(WH[40],WH[41],WH[42],WH[43],WH[44],WH[45],WH[46],WH[47]);
    PIN8(WH[48],WH[49],WH[50],WH[51],WH[52],WH[53],WH[54],WH[55]);
    PIN8(WH[56],WH[57],WH[58],WH[59],WH[60],WH[61],WH[62],WH[63]);
#undef PIN8

    // ---- per-thread bias + register-resident c state ----
    const float* bias = layer ? b2 : b1;
    const int gb = tid >> 3;                    // batch row within half (0..31)
    const int gcl0 = (tid * 2) & 15;            // even cell pair base
    float bias_q[2][4];
#pragma unroll
    for (int q = 0; q < 2; ++q) {
        int n = nb * 16 + gcl0 + q; if (n > HH - 1) n = HH - 1;
#pragma unroll
        for (int g = 0; g < 4; ++g) bias_q[q][g] = bias[(size_t)g * HH + n];
    }
    float creg[2] = {0.f, 0.f};

    __shared__ float zs[4][32][68];   // one slab per wave; stride 272B
    __syncthreads();                  // s_ldr visible

#pragma unroll 1
    for (int t = 0; t <= TT; ++t) {
        const bool active = layer ? (t >= 1) : (t <= TT - 1);
        if (active) {
            const char *pAh;
            char *poh;
            if (layer == 0) {
                if (op == 0) pAh = (const char*)xfh + (size_t)t * 131072;
                else         pAh = h1ring + (size_t)((t - 1) & (RING - 1)) * 131072;
                poh = (char*)(h1ring + (size_t)(t & (RING - 1)) * 131072);
            } else {
                if (op == 0) pAh = h1ring + (size_t)((t - 1) & (RING - 1)) * 131072;
                else         pAh = h2ring + (size_t)((t - 2) & (RING - 1)) * 131072;
                poh = (char*)(h2ring + (size_t)((t - 1) & (RING - 1)) * 131072);
            }
            pAh += ((size_t)kh * 4096 + bh * 128 + lane) * 16;

            f32x4 acc[4][2];
#pragma unroll
            for (int tl = 0; tl < 4; ++tl)
#pragma unroll
                for (int mt = 0; mt < 2; ++mt) acc[tl][mt] = (f32x4){0.f, 0.f, 0.f, 0.f};

            bf16x8 rh[8][2];
#define LDB(s, k) do { _Pragma("unroll") \
    for (int mt = 0; mt < 2; ++mt) \
        ld_a(&rh[s][mt], pAh + (size_t)((k) * 256 + mt * 64) * 16); \
    } while (0)
#define CPK(k, s) do { _Pragma("unroll") \
    for (int tl = 0; tl < 4; ++tl) { \
        bf16x8 wh_ = asbf(WH[tl * 16 + (k)]); \
        _Pragma("unroll") \
        for (int mt = 0; mt < 2; ++mt) \
            acc[tl][mt] = __builtin_amdgcn_mfma_f32_16x16x32_bf16(rh[s][mt], wh_, acc[tl][mt], 0, 0, 0); \
    } } while (0)

            LDB(0, 0); LDB(1, 1); LDB(2, 2); LDB(3, 3);
            LDB(4, 4); LDB(5, 5); LDB(6, 6); LDB(7, 7);
#pragma unroll
            for (int ks = 0; ks < 16; ++ks) {
                // 8-slot ring, 2 loads/slot
                if (ks <= 8)       asm volatile("s_waitcnt vmcnt(14)" ::: "memory");
                else if (ks == 9)  asm volatile("s_waitcnt vmcnt(12)" ::: "memory");
                else if (ks == 10) asm volatile("s_waitcnt vmcnt(10)" ::: "memory");
                else if (ks == 11) asm volatile("s_waitcnt vmcnt(8)"  ::: "memory");
                else if (ks == 12) asm volatile("s_waitcnt vmcnt(6)"  ::: "memory");
                else if (ks == 13) asm volatile("s_waitcnt vmcnt(4)"  ::: "memory");
                else if (ks == 14) asm volatile("s_waitcnt vmcnt(2)"  ::: "memory");
                else               asm volatile("s_waitcnt vmcnt(0)"  ::: "memory");
                __builtin_amdgcn_sched_barrier(0);
                CPK(ks, ks & 7);
                if (ks < 8) LDB(ks & 7, ks + 8);
            }
#undef LDB
#undef CPK

            // ---- one-stage z reduction: each wave writes its own slab ----
#pragma unroll
            for (int tl = 0; tl < 4; ++tl)
#pragma unroll
                for (int mt = 0; mt < 2; ++mt)
#pragma unroll
                    for (int r = 0; r < 4; ++r)
                        zs[w][mt * 16 + kg * 4 + r][tl * 16 + ln] = acc[tl][mt][r];
            __syncthreads();

            // ---- fused gates + direct atomic-swap h store (2 cells/thread) ----
            {
                int cc = (gcl0 >> 2) * 16 + (gcl0 & 3) * 4;
                float hv2[2];
#pragma unroll
                for (int q = 0; q < 2; ++q) {
                    float zg[4];
#pragma unroll
                    for (int g = 0; g < 4; ++g)
                        zg[g] = zs[0][gb][cc + q * 4 + g] + zs[1][gb][cc + q * 4 + g]
                              + zs[2][gb][cc + q * 4 + g] + zs[3][gb][cc + q * 4 + g]
                              + bias_q[q][g];
                    float ig = 1.f / (1.f + __expf(-zg[0]));
                    float fg = 1.f / (1.f + __expf(-zg[1]));
                    float gg = 1.f - 2.f / (__expf(2.f * zg[2]) + 1.f);
                    float og = 1.f / (1.f + __expf(-zg[3]));
                    float cn = fg * creg[q] + ig * gg;
                    creg[q] = cn;
                    hv2[q] = og * (1.f - 2.f / (__expf(2.f * cn) + 1.f));
                }
                if (nb * 16 + gcl0 < HH) {
                    unsigned pk = (unsigned)__builtin_bit_cast(unsigned short, (__bf16)hv2[0])
                                | ((unsigned)__builtin_bit_cast(unsigned short, (__bf16)hv2[1]) << 16);
                    int mt_l = gb >> 4, lnn = gb & 15;
                    int kgsel = gcl0 >> 3, j0 = gcl0 & 7;
                    size_t unit = (((size_t)(nb >> 1) * 4 + bh * 2 + mt_l) * 64)
                                + ((nb & 1) * 2 + kgsel) * 16 + lnn;
                    st_h32(poh + unit * 16 + (size_t)j0 * 2, pk);
                }
            }
            // drain this wave's h atomics (at L3 when counted)
            asm volatile("s_waitcnt vmcnt(0)" ::: "memory");
        }

        // ---- flat store/observe barrier via L3 atomics; boundary inv (r16) ----
        if (t < TT) {
            __syncthreads();          // all waves' h stores drained
            const unsigned tp1 = (unsigned)(t + 1);
            if (w == 0) {
                if (tid == 0) st_ctl(arr + (size_t)bid * 4, tp1);
                const unsigned* a0 = arr + (size_t)lane * 4;
                bool done = false;
                while (!done) {
                    unsigned v0 = ld_ctl(a0);
                    unsigned v1 = ld_ctl(a0 + 256);
                    unsigned v2 = ld_ctl(a0 + 512);
                    unsigned v3 = ld_ctl(a0 + 768);
                    asm volatile("s_waitcnt vmcnt(0)" ::: "memory");
                    bool ok = (v0 >= tp1) && (v1 >= tp1) && (v2 >= tp1)
                           && ((lane + 192 >= NBLK) || (v3 >= tp1));
                    done = __all(ok);
                    if (!done) __builtin_amdgcn_s_sleep(1);
                }
                if ((tp1 & (RING - 1u)) == 0u) {
                    if (tid == 0) {
                        unsigned info = s_ldr;
                        unsigned* fP = xcdFlag + (info >> 8) * 16;
                        if (info & 1u) {
                            __builtin_amdgcn_fence(__ATOMIC_ACQUIRE, "agent");
                            asm volatile("s_waitcnt vmcnt(0) lgkmcnt(0)" ::: "memory");
                            __hip_atomic_store(fP, tp1, AT_RLX, SC_AGT);
                        } else {
                            while (__hip_atomic_load(fP, AT_RLX, SC_AGT) < tp1)
                                __builtin_amdgcn_s_sleep(1);
                        }
                    }
                    __builtin_amdgcn_wave_barrier();
                }
            }
            __syncthreads();
        }
    }
}

// ---------------------------------------------------------------------------
// out[b][o] = bo[o] + sum_n h2[b][n] * Wo[n][o] ; h2 (bf16) in fragment order
__global__ void out_proj(const __bf16* __restrict__ h2h,
                         const float* __restrict__ Wo, const float* __restrict__ bo,
                         float* __restrict__ out)
{
    int b = blockIdx.x, tid = threadIdx.x;
    int mt = b >> 4, ln = b & 15;
    float acc[6] = {0, 0, 0, 0, 0, 0};
    for (int n = tid; n < HH; n += 256) {
        int ks = n >> 5, kg = (n >> 3) & 3, j = n & 7;
        size_t idx = (((size_t)ks * 4 + mt) * 64 + kg * 16 + ln) * 8 + j;
        float h = (float)h2h[idx];
#pragma unroll
        for (int o = 0; o < 6; ++o) acc[o] += h * Wo[n * 6 + o];
    }
#pragma unroll
    for (int o = 0; o < 6; ++o)
        for (int off = 32; off; off >>= 1) acc[o] += __shfl_down(acc[o], off, 64);
    __shared__ float red[4][6];
    int lane = tid & 63, wv = tid >> 6;
    if (lane == 0) {
#pragma unroll
        for (int o = 0; o < 6; ++o) red[wv][o] = acc[o];
    }
    __syncthreads();
    if (tid < 6) {
        float s = bo[tid];
#pragma unroll
        for (int w = 0; w < 4; ++w) s += red[w][tid];
        out[b * 6 + tid] = s;
    }
}

// ---------------------------------------------------------------------------
extern "C" void kernel_launch(void* const* d_in, const int* in_sizes, int n_in,
                              void* d_out, int out_size, void* d_ws, size_t ws_size,
                              hipStream_t stream) {
    const float* x  = (const float*)d_in[0];
    const float* W1 = (const float*)d_in[1];
    const float* U1 = (const float*)d_in[2];
    const float* b1 = (const float*)d_in[3];
    const float* W2 = (const float*)d_in[4];
    const float* U2 = (const float*)d_in[5];
    const float* b2 = (const float*)d_in[6];
    const float* Wo = (const float*)d_in[7];
    const float* bo = (const float*)d_in[8];
    float* out = (float*)d_out;

    // ws carve: zeroed region first [h rings 4MB, ctrl 8KB]
    char* p = (char*)d_ws;
    __bf16* hbuf = (__bf16*)p; p += (size_t)2 * RING * 65536 * 2;
    unsigned int* ctrl = (unsigned int*)p; p += 8192;
    __bf16* xfh = (__bf16*)p; p += (size_t)8388608 * 2;
    __bf16* w1h = (__bf16*)p; p += (size_t)8192000 * 2;
    __bf16* w2h = (__bf16*)p; p += (size_t)8192000 * 2;

    // ---- preprocessing ----
    zero_ws<<<4104, 256, 0, stream>>>((unsigned int*)d_ws, 1050624);
    cast_x<<<4096, 256, 0, stream>>>(x, xfh);
    pack_w2<<<dim3(250, 2), 256, 0, stream>>>(W1, U1, W2, U2, w1h, w2h);

    // ---- persistent pipelined recurrence (all 129 phases) ----
    lstm_persist<<<NBLK, 256, 0, stream>>>(xfh, w1h, w2h, b1, b2, hbuf, ctrl);

    // h2(127) stored at phase 128 -> h2 ring slot (128-1)&15 = 15
    out_proj<<<64, 256, 0, stream>>>(hbuf + (size_t)(RING + 15) * 65536, Wo, bo, out);
}

// Round 20
// 661.725 us; speedup vs baseline: 3.7028x; 3.7028x over previous
//
#include <hip/hip_runtime.h>
#include <hip/hip_bf16.h>

#define TT 128
#define DD 1024   // padded per-operand K
#define HH 1000
#define NBLK 252  // 2 layers x 2 batch-halves x 63 cell-groups (16 cells each)
#define RING 16   // h ring depth (window); inv every RING phases

typedef float f32x4 __attribute__((ext_vector_type(4)));
typedef __bf16 bf16x8 __attribute__((ext_vector_type(8)));

__device__ __forceinline__ bf16x8 asbf(f32x4 v) { return __builtin_bit_cast(bf16x8, v); }

// A-feed load: sc0 = L1-bypass, L2-CACHEABLE (L2 broadcasts; staleness cleared
// by one buffer_inv per XCD per RING phases — verified r14-r18).
__device__ __forceinline__ void ld_a(bf16x8* d, const char* p) {
    asm volatile("global_load_dwordx4 %0, %1, off sc0" : "=v"(*d) : "v"(p));
}
// h dword store: sc0 sc1 = write-through to the coherence point.
__device__ __forceinline__ void st_h32(char* p, unsigned v) {
    asm volatile("global_store_dword %0, %1, off sc0 sc1" :: "v"(p), "v"(v) : "memory");
}
// barrier slot store
__device__ __forceinline__ void st_ctl(unsigned* p, unsigned v) {
    asm volatile("global_store_dword %0, %1, off sc0 sc1" :: "v"(p), "v"(v) : "memory");
}

#define AT_RLX __ATOMIC_RELAXED
#define SC_AGT __HIP_MEMORY_SCOPE_AGENT

// ---------------------------------------------------------------------------
// zero only the determinism-critical regions: h1 ring slot 15, h2 ring slot
// 15 (each 128 KB), and ctrl (8 KB). 67584 words total.
__global__ void zero_sel(char* __restrict__ ws) {
    int i = blockIdx.x * 256 + threadIdx.x;
    if (i >= 67584) return;
    unsigned* p;
    if (i < 32768)      p = (unsigned*)(ws + (size_t)15 * 131072) + i;
    else if (i < 65536) p = (unsigned*)(ws + (size_t)31 * 131072) + (i - 32768);
    else                p = (unsigned*)(ws + (size_t)32 * 131072) + (i - 65536);
    *p = 0u;
}

// ---------------------------------------------------------------------------
// cast x to bf16 in MFMA A-fragment order (verified):
// unit gid = ((t*32 + ks)*4 + mt)*64 + lane ; elem j = x[mt*16+(lane&15)][t][ks*32+(lane>>4)*8+j]
__global__ void cast_x(const float* __restrict__ x, __bf16* __restrict__ xfh) {
    int gid = blockIdx.x * 256 + threadIdx.x;     // 1,048,576 units
    int lane = gid & 63;
    int mt = (gid >> 6) & 3;
    int ks = (gid >> 8) & 31;
    int t  = gid >> 13;
    int row = mt * 16 + (lane & 15);
    int k0  = ks * 32 + (lane >> 4) * 8;
    const float* sp = x + ((size_t)row * TT + t) * 1024 + k0;
    float4 v0 = *(const float4*)sp;
    float4 v1 = *(const float4*)(sp + 4);
    float f[8] = {v0.x, v0.y, v0.z, v0.w, v1.x, v1.y, v1.z, v1.w};
    bf16x8 hv;
#pragma unroll
    for (int j = 0; j < 8; ++j) hv[j] = (__bf16)f[j];
    ((bf16x8*)xfh)[gid] = hv;
}

// ---------------------------------------------------------------------------
// Fast pack: block = (kb, layer). Loads its 8 k-rows fully COALESCED into a
// 125 KB LDS tile, then writes all 4000 units (byte-identical layout to the
// verified pack_w2: unit = (nt*256+kb)*16+col, elem j = R[kb*8+j][(col&3)*1000
// + nt*4 + (col>>2)], zero-padded rows).
__global__ __launch_bounds__(256) void pack_w3(
    const float* __restrict__ W1, const float* __restrict__ U1,
    const float* __restrict__ W2, const float* __restrict__ U2,
    __bf16* __restrict__ w1h, __bf16* __restrict__ w2h)
{
    int kb = blockIdx.x;          // 0..255
    int layer = blockIdx.y;       // 0..1
    const float* R1 = layer ? W2 : W1;
    const float* R2 = layer ? U2 : U1;
    int k1v = layer ? HH : 1024;
    __bf16* dh = layer ? w2h : w1h;
    int tid = threadIdx.x;

    const float* src = (kb < 128) ? R1 : R2;
    const int kmax = (kb < 128) ? k1v : HH;
    const int base = (kb & 127) * 8;

    __shared__ float lt[8][4008];   // pad 4008: j-stride 8 banks (2-way max)

#pragma unroll 1
    for (int r = 0; r < 8; ++r) {
        bool valid = (base + r) < kmax;
        const float* rp = src + (size_t)(base + r) * 4000;
        for (int c4 = tid; c4 < 1000; c4 += 256) {
            float4 v = valid ? *(const float4*)(rp + c4 * 4)
                             : (float4){0.f, 0.f, 0.f, 0.f};
            lt[r][c4 * 4 + 0] = v.x; lt[r][c4 * 4 + 1] = v.y;
            lt[r][c4 * 4 + 2] = v.z; lt[r][c4 * 4 + 3] = v.w;
        }
    }
    __syncthreads();

    for (int u = tid; u < 4000; u += 256) {
        int nt = u >> 4, col = u & 15;
        int scol = (col & 3) * 1000 + nt * 4 + (col >> 2);
        bf16x8 hv;
#pragma unroll
        for (int j = 0; j < 8; ++j) hv[j] = (__bf16)lt[j][scol];
        size_t unit = ((size_t)nt * 256 + kb) * 16 + col;
        ((bf16x8*)dh)[unit] = hv;
    }
}

// ---------------------------------------------------------------------------
// Persistent LSTM (r18 verbatim — verified 640 us): batch-split, block =
// 32 batch rows x 16 cells; W bf16 in AGPRs; one-stage 4-slab z reduction +
// per-thread direct dword h stores; flat store/observe barrier +
// window-boundary leader buffer_inv.
__global__ __launch_bounds__(256, 1) void lstm_persist(
    const __bf16* __restrict__ xfh,
    const __bf16* __restrict__ w1h, const __bf16* __restrict__ w2h,
    const float* __restrict__ b1, const float* __restrict__ b2,
    __bf16* hbuf, unsigned int* ctrl)
{
    unsigned* xcdm    = ctrl + 32;            // 8 registration counters
    unsigned* xcdFlag = ctrl + 384;           // 8 x 64B-strided flags
    unsigned* arr     = ctrl + 512;           // 256 x 16B-strided arrival slots

    const int bid = blockIdx.x;
    const int layer = bid >= 126;
    const int r0 = layer ? bid - 126 : bid;   // 0..125
    const int bh = r0 >= 63;                  // batch half
    const int nb = bh ? r0 - 63 : r0;         // 0..62 cell-group (16 cells)
    const int tid = threadIdx.x;
    const int lane = tid & 63, w = tid >> 6;
    const int op = w >> 1, kh = w & 1;
    const int ln = lane & 15, kg = lane >> 4;

    const char* h1ring = (const char*)hbuf;
    const char* h2ring = (const char*)(hbuf + (size_t)RING * 65536);

    // ---- startup: XCD registration (leader = first arriver on its XCD) ----
    __shared__ unsigned s_ldr;    // (xcd << 8) | is_leader
    if (tid == 0) {
        unsigned x;
        asm volatile("s_getreg_b32 %0, hwreg(HW_REG_XCC_ID)" : "=s"(x));
        x &= 7u;
        unsigned old = __hip_atomic_fetch_add(&xcdm[x], 1u, AT_RLX, SC_AGT);
        s_ldr = (x << 8) | (old == 0u ? 1u : 0u);
    }

    // ---- preload 4 weight tiles (bf16) into AGPRs: 4 x 16 ks x 4 regs = 256 ----
    const f32x4* wfh = (const f32x4*)(layer ? w2h : w1h);
    f32x4 WH[64];
#pragma unroll
    for (int tl = 0; tl < 4; ++tl) {
        int nt = nb * 4 + tl; if (nt > 249) nt = 249;
#pragma unroll
        for (int ks = 0; ks < 16; ++ks) {
            int kb = op * 128 + kh * 64 + ks * 4 + kg;
            WH[tl * 16 + ks] = wfh[((size_t)nt * 256 + kb) * 16 + ln];
        }
    }
#define PIN8(p0,p1,p2,p3,p4,p5,p6,p7) \
    asm volatile("" : "+a"(p0),"+a"(p1),"+a"(p2),"+a"(p3),"+a"(p4),"+a"(p5),"+a"(p6),"+a"(p7))
    PIN8(WH[0],WH[1],WH[2],WH[3],WH[4],WH[5],WH[6],WH[7]);
    PIN8(WH[8],WH[9],WH[10],WH[11],WH[12],WH[13],WH[14],WH[15]);
    PIN8(WH[16],WH[17],WH[18],WH[19],WH[20],WH[21],WH[22],WH[23]);
    PIN8(WH[24],WH[25],WH[26],WH[27],WH[28],WH[29],WH[30],WH[31]);
    PIN8(WH[32],WH[33],WH[34],WH[35],WH[36],WH[37],WH[38],WH[39]);
    PIN8(WH[40],WH[41],WH[42],WH[43],WH[44],WH[45],WH[46],WH[47]);
    PIN8(WH[48],WH[49],WH[50],WH[51],WH[52],WH[53],WH[54],WH[55]);
    PIN8(WH[56],WH[57],WH[58],WH[59],WH[60],WH[61],WH[62],WH[63]);
#undef PIN8

    // ---- per-thread bias + register-resident c state ----
    const float* bias = layer ? b2 : b1;
    const int gb = tid >> 3;                    // batch row within half (0..31)
    const int gcl0 = (tid * 2) & 15;            // even cell pair base
    float bias_q[2][4];
#pragma unroll
    for (int q = 0; q < 2; ++q) {
        int n = nb * 16 + gcl0 + q; if (n > HH - 1) n = HH - 1;
#pragma unroll
        for (int g = 0; g < 4; ++g) bias_q[q][g] = bias[(size_t)g * HH + n];
    }
    float creg[2] = {0.f, 0.f};

    __shared__ float zs[4][32][68];   // one slab per wave; stride 272B
    __syncthreads();                  // s_ldr visible

#pragma unroll 1
    for (int t = 0; t <= TT; ++t) {
        const bool active = layer ? (t >= 1) : (t <= TT - 1);
        if (active) {
            const char *pAh;
            char *poh;
            if (layer == 0) {
                if (op == 0) pAh = (const char*)xfh + (size_t)t * 131072;
                else         pAh = h1ring + (size_t)((t - 1) & (RING - 1)) * 131072;
                poh = (char*)(h1ring + (size_t)(t & (RING - 1)) * 131072);
            } else {
                if (op == 0) pAh = h1ring + (size_t)((t - 1) & (RING - 1)) * 131072;
                else         pAh = h2ring + (size_t)((t - 2) & (RING - 1)) * 131072;
                poh = (char*)(h2ring + (size_t)((t - 1) & (RING - 1)) * 131072);
            }
            pAh += ((size_t)kh * 4096 + bh * 128 + lane) * 16;

            f32x4 acc[4][2];
#pragma unroll
            for (int tl = 0; tl < 4; ++tl)
#pragma unroll
                for (int mt = 0; mt < 2; ++mt) acc[tl][mt] = (f32x4){0.f, 0.f, 0.f, 0.f};

            bf16x8 rh[8][2];
#define LDB(s, k) do { _Pragma("unroll") \
    for (int mt = 0; mt < 2; ++mt) \
        ld_a(&rh[s][mt], pAh + (size_t)((k) * 256 + mt * 64) * 16); \
    } while (0)
#define CPK(k, s) do { _Pragma("unroll") \
    for (int tl = 0; tl < 4; ++tl) { \
        bf16x8 wh_ = asbf(WH[tl * 16 + (k)]); \
        _Pragma("unroll") \
        for (int mt = 0; mt < 2; ++mt) \
            acc[tl][mt] = __builtin_amdgcn_mfma_f32_16x16x32_bf16(rh[s][mt], wh_, acc[tl][mt], 0, 0, 0); \
    } } while (0)

            LDB(0, 0); LDB(1, 1); LDB(2, 2); LDB(3, 3);
            LDB(4, 4); LDB(5, 5); LDB(6, 6); LDB(7, 7);
#pragma unroll
            for (int ks = 0; ks < 16; ++ks) {
                // 8-slot ring, 2 loads/slot
                if (ks <= 8)       asm volatile("s_waitcnt vmcnt(14)" ::: "memory");
                else if (ks == 9)  asm volatile("s_waitcnt vmcnt(12)" ::: "memory");
                else if (ks == 10) asm volatile("s_waitcnt vmcnt(10)" ::: "memory");
                else if (ks == 11) asm volatile("s_waitcnt vmcnt(8)"  ::: "memory");
                else if (ks == 12) asm volatile("s_waitcnt vmcnt(6)"  ::: "memory");
                else if (ks == 13) asm volatile("s_waitcnt vmcnt(4)"  ::: "memory");
                else if (ks == 14) asm volatile("s_waitcnt vmcnt(2)"  ::: "memory");
                else               asm volatile("s_waitcnt vmcnt(0)"  ::: "memory");
                __builtin_amdgcn_sched_barrier(0);
                CPK(ks, ks & 7);
                if (ks < 8) LDB(ks & 7, ks + 8);
            }
#undef LDB
#undef CPK

            // ---- one-stage z reduction: each wave writes its own slab ----
#pragma unroll
            for (int tl = 0; tl < 4; ++tl)
#pragma unroll
                for (int mt = 0; mt < 2; ++mt)
#pragma unroll
                    for (int r = 0; r < 4; ++r)
                        zs[w][mt * 16 + kg * 4 + r][tl * 16 + ln] = acc[tl][mt][r];
            __syncthreads();

            // ---- fused gates + direct dword h store (2 cells/thread) ----
            {
                int cc = (gcl0 >> 2) * 16 + (gcl0 & 3) * 4;
                float hv2[2];
#pragma unroll
                for (int q = 0; q < 2; ++q) {
                    float zg[4];
#pragma unroll
                    for (int g = 0; g < 4; ++g)
                        zg[g] = zs[0][gb][cc + q * 4 + g] + zs[1][gb][cc + q * 4 + g]
                              + zs[2][gb][cc + q * 4 + g] + zs[3][gb][cc + q * 4 + g]
                              + bias_q[q][g];
                    float ig = 1.f / (1.f + __expf(-zg[0]));
                    float fg = 1.f / (1.f + __expf(-zg[1]));
                    float gg = 1.f - 2.f / (__expf(2.f * zg[2]) + 1.f);
                    float og = 1.f / (1.f + __expf(-zg[3]));
                    float cn = fg * creg[q] + ig * gg;
                    creg[q] = cn;
                    hv2[q] = og * (1.f - 2.f / (__expf(2.f * cn) + 1.f));
                }
                if (nb * 16 + gcl0 < HH) {
                    unsigned pk = (unsigned)__builtin_bit_cast(unsigned short, (__bf16)hv2[0])
                                | ((unsigned)__builtin_bit_cast(unsigned short, (__bf16)hv2[1]) << 16);
                    int mt_l = gb >> 4, lnn = gb & 15;
                    int kgsel = gcl0 >> 3, j0 = gcl0 & 7;
                    size_t unit = (((size_t)(nb >> 1) * 4 + bh * 2 + mt_l) * 64)
                                + ((nb & 1) * 2 + kgsel) * 16 + lnn;
                    st_h32(poh + unit * 16 + (size_t)j0 * 2, pk);
                }
            }
            // drain this wave's h stores
            asm volatile("s_waitcnt vmcnt(0)" ::: "memory");
        }

        // ---- flat store/observe barrier; boundary protocol (verified) ----
        if (t < TT) {
            __syncthreads();          // all waves' h stores drained
            const unsigned tp1 = (unsigned)(t + 1);
            if (w == 0) {
                if (tid == 0) st_ctl(arr + (size_t)bid * 4, tp1);
                const unsigned* a0 = arr + (size_t)lane * 4;
                bool done = false;
                while (!done) {
                    unsigned v0, v1, v2, v3;
                    asm volatile("global_load_dword %0, %1, off sc0 sc1" : "=v"(v0) : "v"(a0));
                    asm volatile("global_load_dword %0, %1, off sc0 sc1" : "=v"(v1) : "v"(a0 + 256));
                    asm volatile("global_load_dword %0, %1, off sc0 sc1" : "=v"(v2) : "v"(a0 + 512));
                    asm volatile("global_load_dword %0, %1, off sc0 sc1" : "=v"(v3) : "v"(a0 + 768));
                    asm volatile("s_waitcnt vmcnt(0)" ::: "memory");
                    bool ok = (v0 >= tp1) && (v1 >= tp1) && (v2 >= tp1)
                           && ((lane + 192 >= NBLK) || (v3 >= tp1));
                    done = __all(ok);
                    if (!done) __builtin_amdgcn_s_sleep(1);
                }
                if ((tp1 & (RING - 1u)) == 0u) {
                    if (tid == 0) {
                        unsigned info = s_ldr;
                        unsigned* fP = xcdFlag + (info >> 8) * 16;
                        if (info & 1u) {
                            __builtin_amdgcn_fence(__ATOMIC_ACQUIRE, "agent");
                            asm volatile("s_waitcnt vmcnt(0) lgkmcnt(0)" ::: "memory");
                            __hip_atomic_store(fP, tp1, AT_RLX, SC_AGT);
                        } else {
                            while (__hip_atomic_load(fP, AT_RLX, SC_AGT) < tp1)
                                __builtin_amdgcn_s_sleep(1);
                        }
                    }
                    __builtin_amdgcn_wave_barrier();
                }
            }
            __syncthreads();
        }
    }
}

// ---------------------------------------------------------------------------
// out[b][o] = bo[o] + sum_n h2[b][n] * Wo[n][o] ; h2 (bf16) in fragment order
__global__ void out_proj(const __bf16* __restrict__ h2h,
                         const float* __restrict__ Wo, const float* __restrict__ bo,
                         float* __restrict__ out)
{
    int b = blockIdx.x, tid = threadIdx.x;
    int mt = b >> 4, ln = b & 15;
    float acc[6] = {0, 0, 0, 0, 0, 0};
    for (int n = tid; n < HH; n += 256) {
        int ks = n >> 5, kg = (n >> 3) & 3, j = n & 7;
        size_t idx = (((size_t)ks * 4 + mt) * 64 + kg * 16 + ln) * 8 + j;
        float h = (float)h2h[idx];
#pragma unroll
        for (int o = 0; o < 6; ++o) acc[o] += h * Wo[n * 6 + o];
    }
#pragma unroll
    for (int o = 0; o < 6; ++o)
        for (int off = 32; off; off >>= 1) acc[o] += __shfl_down(acc[o], off, 64);
    __shared__ float red[4][6];
    int lane = tid & 63, wv = tid >> 6;
    if (lane == 0) {
#pragma unroll
        for (int o = 0; o < 6; ++o) red[wv][o] = acc[o];
    }
    __syncthreads();
    if (tid < 6) {
        float s = bo[tid];
#pragma unroll
        for (int w = 0; w < 4; ++w) s += red[w][tid];
        out[b * 6 + tid] = s;
    }
}

// ---------------------------------------------------------------------------
extern "C" void kernel_launch(void* const* d_in, const int* in_sizes, int n_in,
                              void* d_out, int out_size, void* d_ws, size_t ws_size,
                              hipStream_t stream) {
    const float* x  = (const float*)d_in[0];
    const float* W1 = (const float*)d_in[1];
    const float* U1 = (const float*)d_in[2];
    const float* b1 = (const float*)d_in[3];
    const float* W2 = (const float*)d_in[4];
    const float* U2 = (const float*)d_in[5];
    const float* b2 = (const float*)d_in[6];
    const float* Wo = (const float*)d_in[7];
    const float* bo = (const float*)d_in[8];
    float* out = (float*)d_out;

    // ws carve: [h rings 4MB, ctrl 8KB, xfh, w1h, w2h]
    char* p = (char*)d_ws;
    __bf16* hbuf = (__bf16*)p; p += (size_t)2 * RING * 65536 * 2;
    unsigned int* ctrl = (unsigned int*)p; p += 8192;
    __bf16* xfh = (__bf16*)p; p += (size_t)8388608 * 2;
    __bf16* w1h = (__bf16*)p; p += (size_t)8192000 * 2;
    __bf16* w2h = (__bf16*)p; p += (size_t)8192000 * 2;

    // ---- preprocessing ----
    zero_sel<<<264, 256, 0, stream>>>((char*)d_ws);
    cast_x<<<4096, 256, 0, stream>>>(x, xfh);
    pack_w3<<<dim3(256, 2), 256, 0, stream>>>(W1, U1, W2, U2, w1h, w2h);

    // ---- persistent pipelined recurrence (all 129 phases) ----
    lstm_persist<<<NBLK, 256, 0, stream>>>(xfh, w1h, w2h, b1, b2, hbuf, ctrl);

    // h2(127) stored at phase 128 -> h2 ring slot (128-1)&15 = 15... slot 15
    // is zeroed pre-launch but overwritten at phase 113+16=... (127&15)=15? No:
    // h2(127) written at phase 128 -> slot (128-1)&15 = 15 (overwritten after
    // its zero; read here post-kernel).
    out_proj<<<64, 256, 0, stream>>>(hbuf + (size_t)(RING + 15) * 65536, Wo, bo, out);
}